// Round 11
// baseline (233.234 us; speedup 1.0000x reference)
//
#include <hip/hip_runtime.h>
#include <hip/hip_bf16.h>
#include <cstdint>
#include <cstddef>

#define C_N 100000
#define B_N 512
#define D_N 512

#define COS_M_F   0.87758256189037276f
#define SIN_M_F   0.47942553860420301f
#define THRESH_F  (-0.87758256189037276f)
#define MM_F      0.23971276930210150f
#define S_F       64.0f

typedef __attribute__((ext_vector_type(8))) short short8;
typedef __attribute__((ext_vector_type(4))) float f32x4;

__device__ __forceinline__ unsigned short f2bf(float f) {
  unsigned u = __float_as_uint(f);
  u = u + 0x7fffu + ((u >> 16) & 1u);
  return (unsigned short)(u >> 16);
}

__device__ __forceinline__ float wave_sum(float v) {
#pragma unroll
  for (int o = 32; o > 0; o >>= 1) v += __shfl_down(v, o, 64);
  return v;
}

__device__ __forceinline__ void lds_load16(const void* g, void* l) {
  __builtin_amdgcn_global_load_lds(
      (const __attribute__((address_space(1))) unsigned int*)g,
      (__attribute__((address_space(3))) unsigned int*)l, 16, 0, 0);
}

// ---------------- kernel N1v2 (R3-verified): col-norm + transpose -> Knt -----
__launch_bounds__(512)
__global__ void knorm2_k(const float* __restrict__ Kp, float* __restrict__ cninv,
                         unsigned short* __restrict__ Knt) {
  __shared__ __align__(16) unsigned short Tl[64 * 512];
  __shared__ float ssum[32][64];
  __shared__ float cns[64];

  const int t = threadIdx.x;
  const int j0 = blockIdx.x * 64;
  const int jq = t & 15;
  const int dr = t >> 4;
  const int jcol = min((j0 >> 2) + jq, (C_N >> 2) - 1);
  const float4* __restrict__ Kv = (const float4*)Kp;

  float4 v[16];
#pragma unroll
  for (int i = 0; i < 16; ++i)
    v[i] = Kv[(size_t)(dr * 16 + i) * (C_N / 4) + jcol];

  float s0 = 0.f, s1 = 0.f, s2 = 0.f, s3 = 0.f;
#pragma unroll
  for (int i = 0; i < 16; ++i) {
    s0 = fmaf(v[i].x, v[i].x, s0);
    s1 = fmaf(v[i].y, v[i].y, s1);
    s2 = fmaf(v[i].z, v[i].z, s2);
    s3 = fmaf(v[i].w, v[i].w, s3);
  }
  ssum[dr][jq * 4 + 0] = s0;
  ssum[dr][jq * 4 + 1] = s1;
  ssum[dr][jq * 4 + 2] = s2;
  ssum[dr][jq * 4 + 3] = s3;
  __syncthreads();
  if (t < 64) {
    float s = 0.f;
#pragma unroll
    for (int d = 0; d < 32; ++d) s += ssum[d][t];
    float r = rsqrtf(fmaxf(s, 1e-30f));
    cns[t] = r;
    if (j0 + t < C_N) cninv[j0 + t] = r;
  }
  __syncthreads();

  const float r0 = cns[jq * 4 + 0];
  const float r1 = cns[jq * 4 + 1];
  const float r2 = cns[jq * 4 + 2];
  const float r3 = cns[jq * 4 + 3];
#pragma unroll
  for (int g = 0; g < 4; ++g) {
    const int ch = dr * 2 + (g >> 1);
    const int sub = (g & 1) * 8;
#pragma unroll
    for (int c = 0; c < 4; ++c) {
      const int j = jq * 4 + c;
      const float rc = (c == 0) ? r0 : (c == 1) ? r1 : (c == 2) ? r2 : r3;
      unsigned lo, hi;
      lo = (unsigned)f2bf(v[g * 4 + 0][c] * rc) | ((unsigned)f2bf(v[g * 4 + 1][c] * rc) << 16);
      hi = (unsigned)f2bf(v[g * 4 + 2][c] * rc) | ((unsigned)f2bf(v[g * 4 + 3][c] * rc) << 16);
      const int phys = ch ^ (j & 7);
      *(uint2*)((char*)Tl + j * 1024 + phys * 16 + sub) = make_uint2(lo, hi);
    }
  }
  __syncthreads();

  const int jr = t >> 3;
  const int dc = t & 7;
  const int jg = j0 + jr;
  if (jg < C_N) {
#pragma unroll
    for (int s = 0; s < 8; ++s) {
      const int phys = (s * 8) + (dc ^ (jr & 7));
      uint4 val = *(const uint4*)((const char*)Tl + jr * 1024 + phys * 16);
      *(uint4*)(&Knt[(size_t)jg * D_N + s * 64 + dc * 8]) = val;
    }
  }
}

// ---------------- kernel 2: embedding row normalize -> bf16 ------------------
__global__ void embnorm_k(const float* __restrict__ emb, unsigned short* __restrict__ embn,
                          float* __restrict__ rinv) {
  int row = blockIdx.x;
  int t = threadIdx.x;
  float4 v = ((const float4*)(emb + (size_t)row * D_N))[t];
  float ss = v.x * v.x + v.y * v.y + v.z * v.z + v.w * v.w;
  ss = wave_sum(ss);
  __shared__ float red[2];
  if ((t & 63) == 0) red[t >> 6] = ss;
  __syncthreads();
  float tot = red[0] + red[1];
  float ri = rsqrtf(tot);
  if (t == 0) rinv[row] = ri;
  ushort4 o;
  o.x = f2bf(v.x * ri); o.y = f2bf(v.y * ri); o.z = f2bf(v.z * ri); o.w = f2bf(v.w * ri);
  ((ushort4*)(embn + (size_t)row * D_N))[t] = o;
}

// ---------------- kernel 3: target logit (computes own label-col norm) -------
__global__ void target2_k(const float* __restrict__ emb, const float* __restrict__ Kp,
                          const float* __restrict__ rinv, const int* __restrict__ labels,
                          float* __restrict__ target, float* __restrict__ ctm,
                          float* __restrict__ ft) {
  int row = blockIdx.x;
  int t = threadIdx.x;
  int lab = labels[row];
  float p = 0.f, ss = 0.f;
  for (int d = t; d < D_N; d += 256) {
    float kv = Kp[(size_t)d * C_N + lab];
    p = fmaf(emb[(size_t)row * D_N + d], kv, p);
    ss = fmaf(kv, kv, ss);
  }
  p = wave_sum(p);
  ss = wave_sum(ss);
  __shared__ float redp[4], reds[4];
  if ((t & 63) == 0) { redp[t >> 6] = p; reds[t >> 6] = ss; }
  __syncthreads();
  if (t == 0) {
    float dot = redp[0] + redp[1] + redp[2] + redp[3];
    float sums = reds[0] + reds[1] + reds[2] + reds[3];
    float tg = dot * rinv[row] * rsqrtf(fmaxf(sums, 1e-30f));
    tg = fminf(fmaxf(tg, -1.f), 1.f);
    float st = sqrtf(fmaxf(1.f - tg * tg, 0.f));
    float cm = tg * COS_M_F - st * SIN_M_F;
    float f = (tg > THRESH_F) ? cm : (tg - MM_F);
    target[row] = tg;
    ctm[row] = cm;
    ft[row] = f;
  }
}

// ---------------- kernel 4: new_t reduction ----------------------------------
__global__ void newt_k(const float* __restrict__ target, const float* __restrict__ t_in,
                       float* __restrict__ newt) {
  int t = threadIdx.x;
  float v = target[t];
  v = wave_sum(v);
  __shared__ float red[8];
  if ((t & 63) == 0) red[t >> 6] = v;
  __syncthreads();
  if (t == 0) {
    float s = 0.f;
#pragma unroll
    for (int i = 0; i < 8; ++i) s += red[i];
    *newt = 0.01f * (s / (float)B_N) + 0.99f * t_in[0];
  }
}

// ---------------- kernel G12: barrier-free streaming GEMM --------------------
// Block = 64 rows x 256 cols, 8 waves (each 64 x 32). A (64 rows x 512 k,
// 64 KB) staged ONCE into LDS in the verified swizzled chunk layout -> one
// barrier total. K-loop: A frags from read-only LDS, B frags streamed from Knt
// directly to registers with depth-4 rotating prefetch (fully unrolled, static
// indices). No __syncthreads in the loop -> no wave convoy. m-minor bijective
// XCD swizzle co-locates the 8 m-siblings of each j-tile on one XCD so 7/8 of
// B reads hit that XCD's L2. LDS 64 KB -> 2 blocks/CU (16 waves/CU).
__launch_bounds__(512, 4)
__global__ void gemm12_k(const unsigned short* __restrict__ Knt,
                         const unsigned short* __restrict__ embn,
                         const int* __restrict__ labels,
                         const float* __restrict__ ctm, const float* __restrict__ ft,
                         const float* __restrict__ newt_p, float* __restrict__ out) {
  __shared__ __align__(16) unsigned short A[32768];  // 16 chunks x [64 rows][32 k]

  const int t = threadIdx.x;
  const int l = t & 63, w = t >> 6;  // 8 waves

  // bijective XCD swizzle (m204), m-minor logical order: 8 siblings -> same XCD
  const int nwg = gridDim.x;             // 3128 = 8*391
  const int q = nwg >> 3, r = nwg & 7;   // 391, 0
  const int xcd = blockIdx.x & 7, seq = blockIdx.x >> 3;
  const int wg = (xcd < r ? xcd * (q + 1) : r * (q + 1) + (xcd - r) * q) + seq;
  const int mi = wg & 7, jt = wg >> 3;
  const int m0 = mi * 64;
  const int j0 = jt * 256;

  // ---- stage A once: verified source-swizzle <-> linear LDS dest ----------
  const int sidx = (l & 7) ^ (l >> 3);
  const int r0 = ((l >> 3) << 1) | (sidx >> 2);
  const int kc8 = (sidx & 3) * 8;
  {
    const int c0 = w * 2;
#pragma unroll
    for (int cc = 0; cc < 2; ++cc) {
      const int c = c0 + cc;
#pragma unroll
      for (int g = 0; g < 4; ++g)
        lds_load16(embn + (size_t)(m0 + g * 16 + r0) * D_N + c * 32 + kc8,
                   (char*)A + c * 4096 + g * 1024 + l * 16);
    }
  }
  __syncthreads();  // the only block-wide barrier

  const int lq = l >> 4, lr = l & 15;
  const int s16 = ((((lr & 1) << 2) | lq) ^ (lr >> 1)) << 4;
  const int rh = lr >> 1;

  // B stream pointers: rows jn = j0 + w*32 + (nb*16) + lr; Knt padded to 100096
  const unsigned short* b0p = Knt + (size_t)(j0 + w * 32 + lr) * D_N + lq * 8;
  const unsigned short* b1p = b0p + (size_t)16 * D_N;

  f32x4 acc[4][2];
#pragma unroll
  for (int mb = 0; mb < 4; ++mb) {
    acc[mb][0] = 0;
    acc[mb][1] = 0;
  }

  // depth-4 rotating register prefetch (fully unrolled -> static indices)
  short8 pb0[4], pb1[4];
#pragma unroll
  for (int p = 0; p < 4; ++p) {
    pb0[p] = *(const short8*)(b0p + p * 32);
    pb1[p] = *(const short8*)(b1p + p * 32);
  }

#pragma unroll
  for (int it = 0; it < 16; ++it) {
    short8 b0 = pb0[it & 3];
    short8 b1 = pb1[it & 3];
    if (it < 12) {
      pb0[it & 3] = *(const short8*)(b0p + (it + 4) * 32);
      pb1[it & 3] = *(const short8*)(b1p + (it + 4) * 32);
    }
    const char* Ab = (const char*)A + it * 4096;
#pragma unroll
    for (int mb = 0; mb < 4; ++mb) {
      short8 a = *(const short8*)(Ab + ((mb * 8 + rh) << 7) + s16);
      acc[mb][0] = __builtin_amdgcn_mfma_f32_16x16x32_bf16(a, b0, acc[mb][0], 0, 0, 0);
      acc[mb][1] = __builtin_amdgcn_mfma_f32_16x16x32_bf16(a, b1, acc[mb][1], 0, 0, 0);
    }
  }

  // ---- epilogue: params from global (L2-hot); guarded stores ----------------
  const float newt = *newt_p;
#pragma unroll
  for (int mb = 0; mb < 4; ++mb) {
#pragma unroll
    for (int rr = 0; rr < 4; ++rr) {
      const int grow = m0 + mb * 16 + lq * 4 + rr;
      const int lab = labels[grow];
      const float cm = ctm[grow];
      const float f = ft[grow];
#pragma unroll
      for (int nb = 0; nb < 2; ++nb) {
        const int jn = j0 + w * 32 + nb * 16 + lr;
        float c = fminf(fmaxf(acc[mb][nb][rr], -1.f), 1.f);
        float o = (c > cm) ? c * (newt + c) : c;
        o = (jn == lab) ? f : o;
        if (jn < C_N) out[(size_t)grow * C_N + jn] = o * S_F;
      }
    }
  }
}

// ---------------- launch -----------------------------------------------------
extern "C" void kernel_launch(void* const* d_in, const int* in_sizes, int n_in,
                              void* d_out, int out_size, void* d_ws, size_t ws_size,
                              hipStream_t stream) {
  (void)in_sizes; (void)n_in; (void)out_size; (void)ws_size;
  const float* emb = (const float*)d_in[0];
  const int* labels = (const int*)d_in[1];
  const float* Kp = (const float*)d_in[2];
  const float* t_in = (const float*)d_in[3];
  float* out = (float*)d_out;

  char* wsp = (char*)d_ws;
  const size_t KNT_BYTES = (size_t)100096 * D_N * 2;
  unsigned short* Knt = (unsigned short*)(wsp + 0);
  unsigned short* embn = (unsigned short*)(wsp + KNT_BYTES);
  float* cninv  = (float*)(wsp + KNT_BYTES + 524288);
  float* target = (float*)(wsp + KNT_BYTES + 524288 + 400000);
  float* ctm    = (float*)(wsp + KNT_BYTES + 524288 + 400000 + 2048);
  float* ft     = (float*)(wsp + KNT_BYTES + 524288 + 400000 + 2 * 2048);
  float* rinv   = (float*)(wsp + KNT_BYTES + 524288 + 400000 + 3 * 2048);
  float* newt   = (float*)(wsp + KNT_BYTES + 524288 + 400000 + 4 * 2048);

  knorm2_k<<<(C_N + 63) / 64, 512, 0, stream>>>(Kp, cninv, Knt);
  embnorm_k<<<B_N, 128, 0, stream>>>(emb, embn, rinv);
  target2_k<<<B_N, 256, 0, stream>>>(emb, Kp, rinv, labels, target, ctm, ft);
  newt_k<<<1, 512, 0, stream>>>(target, t_in, newt);
  const int jt = (C_N + 255) / 256;  // 391
  gemm12_k<<<jt * 8, 512, 0, stream>>>(Knt, embn, labels, ctm, ft, newt, out);
}

// Round 12
// 191.939 us; speedup vs baseline: 1.2151x; 1.2151x over previous
//
#include <hip/hip_runtime.h>
#include <hip/hip_bf16.h>
#include <cstdint>
#include <cstddef>

#define C_N 100000
#define B_N 512
#define D_N 512

#define COS_M_F   0.87758256189037276f
#define SIN_M_F   0.47942553860420301f
#define THRESH_F  (-0.87758256189037276f)
#define MM_F      0.23971276930210150f
#define S_F       64.0f

typedef __attribute__((ext_vector_type(8))) short short8;
typedef __attribute__((ext_vector_type(4))) float f32x4;

__device__ __forceinline__ unsigned short f2bf(float f) {
  unsigned u = __float_as_uint(f);
  u = u + 0x7fffu + ((u >> 16) & 1u);
  return (unsigned short)(u >> 16);
}

__device__ __forceinline__ float wave_sum(float v) {
#pragma unroll
  for (int o = 32; o > 0; o >>= 1) v += __shfl_down(v, o, 64);
  return v;
}

__device__ __forceinline__ void lds_load16(const void* g, void* l) {
  __builtin_amdgcn_global_load_lds(
      (const __attribute__((address_space(1))) unsigned int*)g,
      (__attribute__((address_space(3))) unsigned int*)l, 16, 0, 0);
}

// ---------------- kernel 2: embedding row normalize -> bf16 ------------------
__global__ void embnorm_k(const float* __restrict__ emb, unsigned short* __restrict__ embn,
                          float* __restrict__ rinv) {
  int row = blockIdx.x;
  int t = threadIdx.x;  // 128 threads, one float4 each
  float4 v = ((const float4*)(emb + (size_t)row * D_N))[t];
  float ss = v.x * v.x + v.y * v.y + v.z * v.z + v.w * v.w;
  ss = wave_sum(ss);
  __shared__ float red[2];
  if ((t & 63) == 0) red[t >> 6] = ss;
  __syncthreads();
  float tot = red[0] + red[1];
  float ri = rsqrtf(tot);
  if (t == 0) rinv[row] = ri;
  ushort4 o;
  o.x = f2bf(v.x * ri); o.y = f2bf(v.y * ri); o.z = f2bf(v.z * ri); o.w = f2bf(v.w * ri);
  ((ushort4*)(embn + (size_t)row * D_N))[t] = o;
}

// ---------------- kernel 3: target logit; computes label-col norm itself -----
__global__ void target2_k(const float* __restrict__ emb, const float* __restrict__ Kp,
                          const float* __restrict__ rinv, const int* __restrict__ labels,
                          float* __restrict__ target, float* __restrict__ ctm,
                          float* __restrict__ ft) {
  int row = blockIdx.x;
  int t = threadIdx.x;  // 256
  int lab = labels[row];
  float p = 0.f, ss = 0.f;
  for (int d = t; d < D_N; d += 256) {
    float kv = Kp[(size_t)d * C_N + lab];
    p = fmaf(emb[(size_t)row * D_N + d], kv, p);
    ss = fmaf(kv, kv, ss);
  }
  p = wave_sum(p);
  ss = wave_sum(ss);
  __shared__ float redp[4], reds[4];
  if ((t & 63) == 0) { redp[t >> 6] = p; reds[t >> 6] = ss; }
  __syncthreads();
  if (t == 0) {
    float dot = redp[0] + redp[1] + redp[2] + redp[3];
    float sums = reds[0] + reds[1] + reds[2] + reds[3];
    float tg = dot * rinv[row] * rsqrtf(fmaxf(sums, 1e-30f));
    tg = fminf(fmaxf(tg, -1.f), 1.f);
    float st = sqrtf(fmaxf(1.f - tg * tg, 0.f));
    float cm = tg * COS_M_F - st * SIN_M_F;
    float f = (tg > THRESH_F) ? cm : (tg - MM_F);
    target[row] = tg;
    ctm[row] = cm;
    ft[row] = f;
  }
}

// ---------------- kernel 4: new_t reduction ----------------------------------
__global__ void newt_k(const float* __restrict__ target, const float* __restrict__ t_in,
                       float* __restrict__ newt) {
  int t = threadIdx.x;  // 512
  float v = target[t];
  v = wave_sum(v);
  __shared__ float red[8];
  if ((t & 63) == 0) red[t >> 6] = v;
  __syncthreads();
  if (t == 0) {
    float s = 0.f;
#pragma unroll
    for (int i = 0; i < 8; ++i) s += red[i];
    *newt = 0.01f * (s / (float)B_N) + 0.99f * t_in[0];
  }
}

// ---------------- kernel G3b: fused colnorm + MFMA GEMM (R4) + PLAIN stores --
// Byte-identical to R4's measured gemm3_k except __builtin_nontemporal_store
// replaced by plain stores (NT inflated WRITE_SIZE 200->290MB, measured R4/R5).
__launch_bounds__(512, 2)
__global__ void gemm3b_k(const float* __restrict__ Kp,
                         const unsigned short* __restrict__ embn,
                         const int* __restrict__ labels,
                         const float* __restrict__ ctm, const float* __restrict__ ft,
                         const float* __restrict__ newt_p, float* __restrict__ out) {
  __shared__ __align__(16) char lds[131072 + 3 * 2048 + 256];
  unsigned short* Bl = (unsigned short*)lds;
  unsigned short* Albase = (unsigned short*)(lds + 65536);
  float* ssum = (float*)(lds + 65536);  // [32][64] aliased with A buf0
  int*   slab = (int*)(lds + 131072);
  float* sctm = (float*)(lds + 131072 + 2048);
  float* sft  = (float*)(lds + 131072 + 4096);
  float* cns  = (float*)(lds + 131072 + 6144);

  const int t = threadIdx.x;
  const int j0 = blockIdx.x * 64;

  slab[t] = labels[t];
  sctm[t] = ctm[t];
  sft[t]  = ft[t];

  // ---- phase 1: load K columns (f32, coalesced float4), column sum-squares --
  const int jq = t & 15;
  const int dr = t >> 4;
  const int jcol = min((j0 >> 2) + jq, (C_N >> 2) - 1);
  const float4* __restrict__ Kv = (const float4*)Kp;
  float4 v[16];
#pragma unroll
  for (int i = 0; i < 16; ++i)
    v[i] = Kv[(size_t)(dr * 16 + i) * (C_N / 4) + jcol];

  float s0 = 0.f, s1 = 0.f, s2 = 0.f, s3 = 0.f;
#pragma unroll
  for (int i = 0; i < 16; ++i) {
    s0 = fmaf(v[i].x, v[i].x, s0);
    s1 = fmaf(v[i].y, v[i].y, s1);
    s2 = fmaf(v[i].z, v[i].z, s2);
    s3 = fmaf(v[i].w, v[i].w, s3);
  }
  ssum[dr * 64 + jq * 4 + 0] = s0;
  ssum[dr * 64 + jq * 4 + 1] = s1;
  ssum[dr * 64 + jq * 4 + 2] = s2;
  ssum[dr * 64 + jq * 4 + 3] = s3;
  __syncthreads();
  if (t < 64) {
    float s = 0.f;
#pragma unroll
    for (int d = 0; d < 32; ++d) s += ssum[d * 64 + t];
    cns[t] = rsqrtf(fmaxf(s, 1e-30f));
  }
  __syncthreads();

  // ---- phase 2: issue A prologue loads, then pack B into swizzled LDS ------
  const int l = t & 63, w = t >> 6;
  const int sidx = (l & 7) ^ (l >> 3);
  const int r0 = ((l >> 3) << 1) | (sidx >> 2);
  const int kc8 = (sidx & 3) * 8;
  const unsigned short* asrc = embn + (size_t)(w * 64 + r0) * D_N + kc8;

#pragma unroll
  for (int p = 0; p < 4; ++p)
    lds_load16(asrc + p * 16 * D_N, Albase + w * 2048 + p * 512);

  // B pack: byte = itile*4096 + (n>>1)*128 + ((((n&1)<<2)|c) ^ ((n>>1)&7))*16
  {
    const float rc0 = cns[jq * 4 + 0];
    const float rc1 = cns[jq * 4 + 1];
    const float rc2 = cns[jq * 4 + 2];
    const float rc3 = cns[jq * 4 + 3];
    const int itile = dr >> 1;
    const int cbase = (dr & 1) * 2;
#pragma unroll
    for (int cc = 0; cc < 4; ++cc) {
      const int n = jq * 4 + cc;
      const int rowp = n >> 1;
      const int nb = (n & 1) << 2;
      const int x7 = rowp & 7;
      const float rc = (cc == 0) ? rc0 : (cc == 1) ? rc1 : (cc == 2) ? rc2 : rc3;
#pragma unroll
      for (int h = 0; h < 2; ++h) {
        unsigned w0 = (unsigned)f2bf(v[h * 8 + 0][cc] * rc) | ((unsigned)f2bf(v[h * 8 + 1][cc] * rc) << 16);
        unsigned w1 = (unsigned)f2bf(v[h * 8 + 2][cc] * rc) | ((unsigned)f2bf(v[h * 8 + 3][cc] * rc) << 16);
        unsigned w2 = (unsigned)f2bf(v[h * 8 + 4][cc] * rc) | ((unsigned)f2bf(v[h * 8 + 5][cc] * rc) << 16);
        unsigned w3 = (unsigned)f2bf(v[h * 8 + 6][cc] * rc) | ((unsigned)f2bf(v[h * 8 + 7][cc] * rc) << 16);
        char* dst = (char*)Bl + itile * 4096 + rowp * 128 + ((nb | (cbase + h)) ^ x7) * 16;
        *(uint4*)dst = make_uint4(w0, w1, w2, w3);
      }
    }
  }
  __syncthreads();  // drains B ds_writes AND A prologue vmcnt

  // ---- phase 3: K-loop (A dbuf via global_load_lds, B resident) -------------
  const int wr = w >> 1, wc = w & 1;
  const int lq = l >> 4, lr = l & 15;
  const int s16 = ((((lr & 1) << 2) | lq) ^ (lr >> 1)) << 4;
  const int rh = lr >> 1;
  const float newt = *newt_p;

  f32x4 acc[8][2];
#pragma unroll
  for (int mb = 0; mb < 8; ++mb) {
    acc[mb][0] = 0;
    acc[mb][1] = 0;
  }

#pragma unroll
  for (int it = 0; it < 16; ++it) {
    const int cur = it & 1, nxt = cur ^ 1;
    if (it < 15) {
      const int k0 = (it + 1) * 32;
#pragma unroll
      for (int p = 0; p < 4; ++p)
        lds_load16(asrc + p * 16 * D_N + k0, Albase + nxt * 16384 + w * 2048 + p * 512);
    }
    const char* Ab = (const char*)(Albase + cur * 16384);
    const char* Bt = (const char*)Bl + it * 4096;
    short8 b0 = *(const short8*)(Bt + ((wc * 16 + 0 + rh) << 7) + s16);
    short8 b1 = *(const short8*)(Bt + ((wc * 16 + 8 + rh) << 7) + s16);
#pragma unroll
    for (int mb = 0; mb < 8; ++mb) {
      short8 a = *(const short8*)(Ab + ((wr * 64 + mb * 8 + rh) << 7) + s16);
      acc[mb][0] = __builtin_amdgcn_mfma_f32_16x16x32_bf16(a, b0, acc[mb][0], 0, 0, 0);
      acc[mb][1] = __builtin_amdgcn_mfma_f32_16x16x32_bf16(a, b1, acc[mb][1], 0, 0, 0);
    }
    __syncthreads();
  }

  // ---- epilogue (B pre-normalized; PLAIN stores) ----------------------------
  const int jn0 = j0 + wc * 32 + lr;
  const int jn1 = jn0 + 16;
#pragma unroll
  for (int mb = 0; mb < 8; ++mb) {
    int ibase = wr * 128 + mb * 16 + 4 * lq;
#pragma unroll
    for (int r = 0; r < 4; ++r) {
      int i = ibase + r;
      int lab = slab[i];
      float cm = sctm[i];
      float f = sft[i];
      {
        float c = fminf(fmaxf(acc[mb][0][r], -1.f), 1.f);
        float o = (c > cm) ? c * (newt + c) : c;
        o = (jn0 == lab) ? f : o;
        if (jn0 < C_N) out[(size_t)i * C_N + jn0] = o * S_F;
      }
      {
        float c = fminf(fmaxf(acc[mb][1][r], -1.f), 1.f);
        float o = (c > cm) ? c * (newt + c) : c;
        o = (jn1 == lab) ? f : o;
        if (jn1 < C_N) out[(size_t)i * C_N + jn1] = o * S_F;
      }
    }
  }
}

// ---------------- launch -----------------------------------------------------
extern "C" void kernel_launch(void* const* d_in, const int* in_sizes, int n_in,
                              void* d_out, int out_size, void* d_ws, size_t ws_size,
                              hipStream_t stream) {
  (void)in_sizes; (void)n_in; (void)out_size; (void)ws_size;
  const float* emb = (const float*)d_in[0];
  const int* labels = (const int*)d_in[1];
  const float* Kp = (const float*)d_in[2];
  const float* t_in = (const float*)d_in[3];
  float* out = (float*)d_out;

  char* wsp = (char*)d_ws;
  unsigned short* embn = (unsigned short*)(wsp + 0);   // 524288 B
  float* target = (float*)(wsp + 524288);              // 2048 B
  float* ctm    = (float*)(wsp + 526336);              // 2048 B
  float* ft     = (float*)(wsp + 528384);              // 2048 B
  float* rinv   = (float*)(wsp + 530432);              // 2048 B
  float* newt   = (float*)(wsp + 532480);              // 4 B

  embnorm_k<<<B_N, 128, 0, stream>>>(emb, embn, rinv);
  target2_k<<<B_N, 256, 0, stream>>>(emb, Kp, rinv, labels, target, ctm, ft);
  newt_k<<<1, 512, 0, stream>>>(target, t_in, newt);
  gemm3b_k<<<(C_N + 63) / 64, 512, 0, stream>>>(Kp, embn, labels, ctm, ft, newt, out);
}